// Round 1
// baseline (326.293 us; speedup 1.0000x reference)
//
#include <hip/hip_runtime.h>

typedef unsigned short u16;
typedef unsigned int u32;
typedef __attribute__((ext_vector_type(8))) short bf16x8;   // 8 bf16 = 4 VGPRs
typedef __attribute__((ext_vector_type(4))) float f32x4;
typedef __attribute__((ext_vector_type(16))) float f32x16;
typedef __attribute__((ext_vector_type(4))) float floatx4;
typedef __attribute__((ext_vector_type(4))) u16 u16x4;

__device__ __forceinline__ u16 f2bf(float x) {
  union { float f; u32 u; } c; c.f = x;
  return (u16)((c.u + 0x7fffu + ((c.u >> 16) & 1u)) >> 16);  // RNE
}
__device__ __forceinline__ u32 packbf(float a, float b) {
  return (u32)f2bf(a) | ((u32)f2bf(b) << 16);
}

__device__ __forceinline__ void gload16(const u16* g, u16* l) {
  auto gp = (const __attribute__((address_space(1))) unsigned int*)g;
  auto lp = (__attribute__((address_space(3))) unsigned int*)l;
  __builtin_amdgcn_global_load_lds(gp, lp, 16, 0, 0);
}

// ---------------- fp32 -> bf16 conversion (up to 4 tensors per launch) -------
__global__ void cvt_bf16(const float* s0, const float* s1, const float* s2, const float* s3,
                         u16* d0, u16* d1, u16* d2, u16* d3, int n4) {
  const float* sp[4] = {s0, s1, s2, s3};
  u16* dp[4] = {d0, d1, d2, d3};
  const float* s = sp[blockIdx.y];
  u16* d = dp[blockIdx.y];
  int i = blockIdx.x * 256 + threadIdx.x;
  if (i < n4) {
    floatx4 v = ((const floatx4*)s)[i];
    u16x4 o;
    o.x = f2bf(v.x); o.y = f2bf(v.y); o.z = f2bf(v.z); o.w = f2bf(v.w);
    ((u16x4*)d)[i] = o;
  }
}

// ---------------- 128x128 tile GEMM, C = A @ W^T + b (A:[4096,1024], W:[1024,1024])
// MODE 0: bf16 out, head layout [N=2][H=16][L=2048][64]
// MODE 1: bf16 out, transposed head layout [N][H][64][2048]  (for V)
// MODE 2: f32 out, plain row-major [4096][1024]
template<int MODE>
__global__ __launch_bounds__(256) void gemm_bt(const u16* __restrict__ A,
                                               const u16* __restrict__ Bw,
                                               const float* __restrict__ bias,
                                               void* __restrict__ outp) {
  __shared__ u16 lA[128 * 32];
  __shared__ u16 lB[128 * 32];
  const int tid = threadIdx.x;
  const int brow = blockIdx.y * 128, bcol = blockIdx.x * 128;
  const int lane = tid & 63, w = tid >> 6;
  const int wr = w >> 1, wc = w & 1;
  const int fr = lane & 15, fq = lane >> 4;
  f32x4 acc[4][4] = {};

  for (int k0 = 0; k0 < 1024; k0 += 32) {
    __syncthreads();
#pragma unroll
    for (int it = 0; it < 2; ++it) {
      int chunk = tid + it * 256;       // 16B chunks of the 8KB tile
      int row = chunk >> 2;             // [128][32] bf16 row-major
      int col = (chunk & 3) * 8;
      gload16(A  + (size_t)(brow + row) * 1024 + k0 + col, &lA[chunk * 8]);
      gload16(Bw + (size_t)(bcol + row) * 1024 + k0 + col, &lB[chunk * 8]);
    }
    __syncthreads();
    bf16x8 af[4], bfr[4];
#pragma unroll
    for (int m = 0; m < 4; ++m) af[m]  = *(const bf16x8*)&lA[(wr * 64 + m * 16 + fr) * 32 + fq * 8];
#pragma unroll
    for (int n = 0; n < 4; ++n) bfr[n] = *(const bf16x8*)&lB[(wc * 64 + n * 16 + fr) * 32 + fq * 8];
#pragma unroll
    for (int m = 0; m < 4; ++m)
#pragma unroll
      for (int n = 0; n < 4; ++n)
        acc[m][n] = __builtin_amdgcn_mfma_f32_16x16x32_bf16(af[m], bfr[n], acc[m][n], 0, 0, 0);
  }

#pragma unroll
  for (int m = 0; m < 4; ++m) {
#pragma unroll
    for (int n = 0; n < 4; ++n) {
      int colg = bcol + wc * 64 + n * 16 + fr;
      float bv = bias[colg];
#pragma unroll
      for (int j = 0; j < 4; ++j) {
        int rowg = brow + wr * 64 + m * 16 + fq * 4 + j;   // C: col=lane&15, row=(lane>>4)*4+reg
        float v = acc[m][n][j] + bv;
        if (MODE == 2) {
          ((float*)outp)[(size_t)rowg * 1024 + colg] = v;
        } else {
          int nb = rowg >> 11, l = rowg & 2047;
          int h = colg >> 6, dd = colg & 63;
          size_t idx;
          if (MODE == 0) idx = ((size_t)(nb * 16 + h) * 2048 + l) * 64 + dd;
          else           idx = ((size_t)(nb * 16 + h) * 64 + dd) * 2048 + l;
          ((u16*)outp)[idx] = f2bf(v);
        }
      }
    }
  }
}

// ---------------- causal flash attention --------------------------------------
// Q,K: [NH=32][2048][64] bf16; V^T: [NH][64][2048] bf16; out attn: [4096][1024] bf16
// 4 waves/block, wave owns 32 q-rows. Swapped QK^T: S^T = mfma(K, Q) so each lane
// holds one q-column (col=lane&31) -> softmax is lane-local + one shfl_xor(32).
__global__ __launch_bounds__(256) void attn_fwd(const u16* __restrict__ Qp,
                                                const u16* __restrict__ Kp,
                                                const u16* __restrict__ Vt,
                                                u16* __restrict__ attn) {
  const int lane = threadIdx.x & 63, w = threadIdx.x >> 6;
  const int nh = blockIdx.y;
  const int q0 = blockIdx.x * 128 + w * 32;
  const int col = lane & 31, hi = lane >> 5;
  const u16* Q = Qp + (size_t)nh * 2048 * 64;
  const u16* K = Kp + (size_t)nh * 2048 * 64;
  const u16* V = Vt + (size_t)nh * 64 * 2048;
  const int q = q0 + col;
  const float kscale = 0.125f * 1.44269504089f;   // 1/sqrt(64) * log2(e), base-2 softmax

  bf16x8 qf[4];
#pragma unroll
  for (int ks = 0; ks < 4; ++ks) qf[ks] = *(const bf16x8*)&Q[(size_t)q * 64 + ks * 16 + hi * 8];

  f32x16 acc0 = {}, acc1 = {};   // out^T tiles: d in [0,32) and [32,64)
  float mrow = -1e30f, lrow = 0.f;

  for (int s0 = 0; s0 <= q0; s0 += 32) {
    f32x16 sc = {};
#pragma unroll
    for (int ks = 0; ks < 4; ++ks) {
      bf16x8 kf = *(const bf16x8*)&K[(size_t)(s0 + col) * 64 + ks * 16 + hi * 8];
      sc = __builtin_amdgcn_mfma_f32_32x32x16_bf16(kf, qf[ks], sc, 0, 0, 0);
    }
    // lane holds S^T[s][q] for fixed q=col: s-rows sr=(r&3)+8*(r>>2)+4*hi
    float pr[16];
    float pmax = -1e30f;
    const bool diag = (s0 == q0);
#pragma unroll
    for (int r = 0; r < 16; ++r) {
      int sr = (r & 3) + 8 * (r >> 2) + 4 * hi;
      float v = sc[r] * kscale;
      if (diag && sr > col) v = -1e30f;            // causal mask on diagonal tile
      pr[r] = v;
      pmax = fmaxf(pmax, v);
    }
    pmax = fmaxf(pmax, __shfl_xor(pmax, 32));
    float mnew = fmaxf(mrow, pmax);
    float alpha = exp2f(mrow - mnew);
    float ps = 0.f;
#pragma unroll
    for (int r = 0; r < 16; ++r) { float p = exp2f(pr[r] - mnew); pr[r] = p; ps += p; }
    ps += __shfl_xor(ps, 32);
    lrow = lrow * alpha + ps;
    mrow = mnew;
#pragma unroll
    for (int r = 0; r < 16; ++r) { acc0[r] *= alpha; acc1[r] *= alpha; }

    // Build PV B-operand (P^T as s x q), exchanging halves with lane^32
#pragma unroll
    for (int ks = 0; ks < 2; ++ks) {
      u32 A0 = packbf(pr[8 * ks + 0], pr[8 * ks + 1]);
      u32 A1 = packbf(pr[8 * ks + 2], pr[8 * ks + 3]);
      u32 B0 = packbf(pr[8 * ks + 4], pr[8 * ks + 5]);
      u32 B1 = packbf(pr[8 * ks + 6], pr[8 * ks + 7]);
      u32 t0 = __shfl_xor(hi ? A0 : B0, 32);
      u32 t1 = __shfl_xor(hi ? A1 : B1, 32);
      union { u32 u[4]; bf16x8 v; } pf;
      pf.u[0] = hi ? t0 : A0;
      pf.u[1] = hi ? t1 : A1;
      pf.u[2] = hi ? B0 : t0;
      pf.u[3] = hi ? B1 : t1;
      bf16x8 vf0 = *(const bf16x8*)&V[(size_t)(col) * 2048 + s0 + ks * 16 + hi * 8];
      bf16x8 vf1 = *(const bf16x8*)&V[(size_t)(32 + col) * 2048 + s0 + ks * 16 + hi * 8];
      acc0 = __builtin_amdgcn_mfma_f32_32x32x16_bf16(vf0, pf.v, acc0, 0, 0, 0);
      acc1 = __builtin_amdgcn_mfma_f32_32x32x16_bf16(vf1, pf.v, acc1, 0, 0, 0);
    }
  }

  const float inv = 1.f / lrow;
  const int nb = nh >> 4, h = nh & 15;
  const size_t arow = (size_t)(nb * 2048 + q) * 1024 + h * 64;
#pragma unroll
  for (int rp = 0; rp < 8; ++rp) {
    int r = rp * 2;
    int d = (r & 3) + 8 * (r >> 2) + 4 * hi;
    *(u32*)&attn[arow + d]      = packbf(acc0[r] * inv, acc0[r + 1] * inv);
    *(u32*)&attn[arow + 32 + d] = packbf(acc1[r] * inv, acc1[r + 1] * inv);
  }
}

// -----------------------------------------------------------------------------
extern "C" void kernel_launch(void* const* d_in, const int* in_sizes, int n_in,
                              void* d_out, int out_size, void* d_ws, size_t ws_size,
                              hipStream_t stream) {
  const float* queries = (const float*)d_in[0];
  const float* keys    = (const float*)d_in[1];
  const float* values  = (const float*)d_in[2];
  const float* Wq = (const float*)d_in[3]; const float* bq = (const float*)d_in[4];
  const float* Wk = (const float*)d_in[5]; const float* bk = (const float*)d_in[6];
  const float* Wv = (const float*)d_in[7]; const float* bv = (const float*)d_in[8];
  const float* Wo = (const float*)d_in[9]; const float* bo = (const float*)d_in[10];
  float* out = (float*)d_out;
  char* ws = (char*)d_ws;

  const size_t MB = 1u << 20;
  u16* xq  = (u16*)(ws + 0 * MB);    // 8 MB  (also reused as attn output later)
  u16* xk  = (u16*)(ws + 8 * MB);
  u16* xv  = (u16*)(ws + 16 * MB);
  u16* wqb = (u16*)(ws + 24 * MB);   // 2 MB each
  u16* wkb = (u16*)(ws + 26 * MB);
  u16* wvb = (u16*)(ws + 28 * MB);
  u16* wob = (u16*)(ws + 30 * MB);
  u16* qp  = (u16*)(ws + 32 * MB);   // 8 MB
  u16* kp  = (u16*)(ws + 40 * MB);
  u16* vt  = (u16*)(ws + 48 * MB);
  u16* at  = xq;                     // attn out reuses xq (dead after Q-proj)

  // fp32 -> bf16
  cvt_bf16<<<dim3(4096, 3), 256, 0, stream>>>(queries, keys, values, nullptr,
                                              xq, xk, xv, nullptr, 1048576);
  cvt_bf16<<<dim3(1024, 4), 256, 0, stream>>>(Wq, Wk, Wv, Wo,
                                              wqb, wkb, wvb, wob, 262144);
  // projections
  gemm_bt<0><<<dim3(8, 32), 256, 0, stream>>>(xq, wqb, bq, qp);
  gemm_bt<0><<<dim3(8, 32), 256, 0, stream>>>(xk, wkb, bk, kp);
  gemm_bt<1><<<dim3(8, 32), 256, 0, stream>>>(xv, wvb, bv, vt);
  // attention
  attn_fwd<<<dim3(16, 32), 256, 0, stream>>>(qp, kp, vt, at);
  // output projection
  gemm_bt<2><<<dim3(8, 32), 256, 0, stream>>>(at, wob, bo, out);
}